// Round 6
// baseline (311.976 us; speedup 1.0000x reference)
//
#include <hip/hip_runtime.h>
#include <stdint.h>

// ---------------------------------------------------------------------------
// DetectionHead: RoIAlign(1000 rois, 256ch, 7x7, SR=2) + 2-branch MLP.
// R6: strip-prep for weight transposes (one block per 64-row k-strip loops
// all 16 n-tiles -> each source segment fetched once, L2-hot), full-K gemm2
// and final with fused bias/relu epilogues (8 -> 6 dispatches, no reduce2/3).
// gemm1/reduce1/roialign unchanged from R5 (measured: 71.5us, 0 conflicts,
// VGPR 52, occ 34.8%).
// ---------------------------------------------------------------------------

#define AS1 __attribute__((address_space(1)))
#define AS3 __attribute__((address_space(3)))

typedef __attribute__((ext_vector_type(8))) short short8;    // 8 bf16 = 4 VGPRs
typedef __attribute__((ext_vector_type(4))) float float4v;   // 16x16 MFMA C/D

#define D_FEAT 12544   // 49*256
#define MPAD   1024    // padded roi count (K=1000)

__device__ __forceinline__ uint16_t f2bf(float f) {
  union { float f; uint32_t u; } v; v.f = f;
  uint32_t r = v.u + 0x7FFFu + ((v.u >> 16) & 1u);   // RNE
  return (uint16_t)(r >> 16);
}
__device__ __forceinline__ float bf2f(uint16_t h) {
  union { uint32_t u; float f; } v; v.u = ((uint32_t)h) << 16;
  return v.f;
}

__device__ __forceinline__ void gll16(const void* g, void* l) {
  __builtin_amdgcn_global_load_lds((const AS1 uint32_t*)g, (AS3 uint32_t*)l, 16, 0, 0);
}

// ---------------------------------------------------------------------------
// prep: tiled transpose + fp32->bf16. Weight transposes use k-strips: one
// block owns 64 consecutive k-rows and loops the 16 n-tiles, so the strided
// 256B source segments are fetched once (same XCD, L2-hot across iters).
// Block ranges:
//   [0,320)    features tiles (nIter=1)
//   [320,712)  W1|Wc1 strips (196 x 2), nIter=16
//   [712,728)  W2 strips (16), nIter=16
//   [728,760)  W3 tiles (kt 16 x nt 2), nIter=1
//   [760,792)  Wc2 tiles, nIter=1
// ---------------------------------------------------------------------------
__global__ __launch_bounds__(256) void prep_kernel(
    const float* __restrict__ features, const float* __restrict__ W1,
    const float* __restrict__ Wc1, const float* __restrict__ W2,
    const float* __restrict__ W3, const float* __restrict__ Wc2,
    uint16_t* __restrict__ featT, uint16_t* __restrict__ w1t,
    uint16_t* __restrict__ w2t, uint16_t* __restrict__ w3t,
    uint16_t* __restrict__ wc2t)
{
  __shared__ __align__(16) uint16_t T[64][72];
  int b = blockIdx.x;
  const float* src; uint16_t* dst;
  int Csrc, Cpad, ldk, rowStride, rowBase, k0, n0, nIter;

  if (b < 320) {
    int img = (b >= 160); int bb = b - img * 160;
    int kt = bb & 3, nt = bb >> 2;
    src = features + (size_t)img * 256 * 2500;
    dst = featT + (size_t)img * 2500 * 256;
    Csrc = 2500; Cpad = 2500; ldk = 256; rowStride = 1;
    k0 = kt * 64; n0 = nt * 64; rowBase = k0; nIter = 1;
  } else if (b < 712) {
    int bb = b - 320; int which = (bb >= 196); bb -= which * 196;
    src = which ? Wc1 : W1;
    dst = w1t + (size_t)(which ? 1024 : 0) * D_FEAT;
    Csrc = 1024; Cpad = 1024; ldk = D_FEAT;
    k0 = bb * 64; n0 = 0; nIter = 16;
    int s = k0 >> 8, c0 = k0 & 255;      // gemm-k k' = s*256 + c -> W row c*49+s
    rowBase = c0 * 49 + s; rowStride = 49;
  } else if (b < 728) {
    int kt = b - 712;
    src = W2; dst = w2t; Csrc = 1024; Cpad = 1024; ldk = 1024;
    rowStride = 1; k0 = kt * 64; n0 = 0; rowBase = k0; nIter = 16;
  } else if (b < 760) {
    int bb = b - 728; int kt = bb & 15, nt = bb >> 4;
    src = W3; dst = w3t; Csrc = 4; Cpad = 128; ldk = 1024;
    rowStride = 1; k0 = kt * 64; n0 = nt * 64; rowBase = k0; nIter = 1;
  } else {
    int bb = b - 760; int kt = bb & 15, nt = bb >> 4;
    src = Wc2; dst = wc2t; Csrc = 81; Cpad = 128; ldk = 1024;
    rowStride = 1; k0 = kt * 64; n0 = nt * 64; rowBase = k0; nIter = 1;
  }

  int t = threadIdx.x;
  int cb = (t & 15) * 4;
  int kb = (t >> 4) * 4;

  for (int it = 0; it < nIter; it++, n0 += 64) {
    float v[4][4];
    if ((Csrc & 3) == 0) {
      int n = n0 + cb;
#pragma unroll
      for (int i = 0; i < 4; i++) {
        if (n < Csrc) {
          const float* p = src + (size_t)(rowBase + (kb + i) * rowStride) * Csrc + n;
          float4 f = *(const float4*)p;
          v[i][0] = f.x; v[i][1] = f.y; v[i][2] = f.z; v[i][3] = f.w;
        } else {
          v[i][0] = v[i][1] = v[i][2] = v[i][3] = 0.f;
        }
      }
    } else {
#pragma unroll
      for (int i = 0; i < 4; i++)
#pragma unroll
        for (int j = 0; j < 4; j++) {
          int n = n0 + cb + j;
          v[i][j] = (n < Csrc) ? src[(size_t)(rowBase + (kb + i) * rowStride) * Csrc + n] : 0.f;
        }
    }
#pragma unroll
    for (int j = 0; j < 4; j++) {
      uint32_t lo = (uint32_t)f2bf(v[0][j]) | ((uint32_t)f2bf(v[1][j]) << 16);
      uint32_t hi = (uint32_t)f2bf(v[2][j]) | ((uint32_t)f2bf(v[3][j]) << 16);
      *(uint2*)&T[cb + j][kb] = make_uint2(lo, hi);
    }
    __syncthreads();
#pragma unroll
    for (int i = 0; i < 2; i++) {
      int n = (t >> 3) + i * 32;
      int c8 = (t & 7) * 8;
      if (n0 + n < Cpad)
        *(uint4*)(dst + (size_t)(n0 + n) * ldk + k0 + c8) = *(const uint4*)&T[n][c8];
    }
    __syncthreads();
  }
}

// ---------------------------------------------------------------------------
// RoIAlign: 128 threads/block, 2 channels per lane (uint loads). Unchanged.
// ---------------------------------------------------------------------------
__global__ __launch_bounds__(128) void roialign_kernel(
    const uint32_t* __restrict__ featT2, const float* __restrict__ props,
    uint32_t* __restrict__ xb2, int K)
{
  __shared__ float wy0[14], wy1[14], wx0[14], wx1[14];
  __shared__ int iy0[14], iy1[14], ix0[14], ix1[14];
  __shared__ int sb;
  int roi = blockIdx.x;
  int t = threadIdx.x;
  if (roi >= K) {
    uint32_t* xr = xb2 + (size_t)roi * (D_FEAT / 2) + t;
    for (int s = 0; s < 49; s++) xr[s * 128] = 0u;
    return;
  }
  if (t < 28) {
    int j = t % 14;
    bool isx = t >= 14;
    const float* p = props + roi * 5;
    float lo = (isx ? p[1] : p[2]) * 0.0625f;
    float hi = (isx ? p[3] : p[4]) * 0.0625f;
    float ext = fmaxf(hi - lo, 1.0f);
    float bin = ext * (1.0f / 7.0f);
    float y = lo + (j + 0.5f) * 0.5f * bin;
    bool valid = (y > -1.0f) && (y < 50.0f);
    float yc = fminf(fmaxf(y, 0.0f), 49.0f);
    int i0 = (int)yc;
    int i1 = min(i0 + 1, 49);
    float fhi = yc - (float)i0;
    float flo = 1.0f - fhi;
    if (!valid) { flo = 0.0f; fhi = 0.0f; }
    if (isx) { ix0[j] = i0; ix1[j] = i1; wx0[j] = flo; wx1[j] = fhi; }
    else     { iy0[j] = i0; iy1[j] = i1; wy0[j] = flo; wy1[j] = fhi; }
  }
  if (t == 0) sb = (int)props[roi * 5];
  __syncthreads();

  const uint32_t* fb = featT2 + (size_t)sb * (2500 * 128) + t;
  uint32_t* xr = xb2 + (size_t)roi * (D_FEAT / 2) + t;
  for (int py = 0; py < 7; py++) {
    for (int px = 0; px < 7; px++) {
      float acc0 = 0.f, acc1 = 0.f;
#pragma unroll
      for (int sy = 0; sy < 2; sy++) {
        int jy = py * 2 + sy;
        int y0 = iy0[jy], y1 = iy1[jy];
        float a0 = wy0[jy], a1 = wy1[jy];
#pragma unroll
        for (int sx = 0; sx < 2; sx++) {
          int jx = px * 2 + sx;
          int x0 = ix0[jx], x1 = ix1[jx];
          float b0 = wx0[jx], b1 = wx1[jx];
          uint32_t u00 = fb[(y0 * 50 + x0) * 128];
          uint32_t u01 = fb[(y0 * 50 + x1) * 128];
          uint32_t u10 = fb[(y1 * 50 + x0) * 128];
          uint32_t u11 = fb[(y1 * 50 + x1) * 128];
          acc0 += a0 * (b0 * bf2f((uint16_t)u00) + b1 * bf2f((uint16_t)u01))
                + a1 * (b0 * bf2f((uint16_t)u10) + b1 * bf2f((uint16_t)u11));
          acc1 += a0 * (b0 * bf2f((uint16_t)(u00 >> 16)) + b1 * bf2f((uint16_t)(u01 >> 16)))
                + a1 * (b0 * bf2f((uint16_t)(u10 >> 16)) + b1 * bf2f((uint16_t)(u11 >> 16)));
        }
      }
      uint32_t packed = (uint32_t)f2bf(acc0 * 0.25f) | ((uint32_t)f2bf(acc1 * 0.25f) << 16);
      xr[(py * 7 + px) * 128] = packed;
    }
  }
}

// ---------------------------------------------------------------------------
// GEMM core: 128x128 C-tile, BK=32, 4 waves, 16x16x32 bf16 MFMA (16/step).
// Measured conflict-free LDS pattern (R2/R5): XOR swizzle on k-group slots.
// ---------------------------------------------------------------------------
__device__ __forceinline__ void gemm_core(
    const uint16_t* __restrict__ A, int lda,
    const uint16_t* __restrict__ BT, int ldb,
    int Mbase, int Nbase, int kStart, int kSteps,
    uint16_t* As, uint16_t* Bs, float4v acc[4][4])
{
  const int t = threadIdx.x;
  const int w = t >> 6, L = t & 63;
  const int wm = (w & 1) * 64, wn = (w >> 1) * 64;

  const int kg = (L & 3) ^ ((L >> 3) & 3);   // XOR swizzle on k-group
  const int rsub = L >> 2;
  const uint16_t* aG0 = A + (size_t)(Mbase + 32 * w + rsub) * lda + kStart + kg * 8;
  const uint16_t* aG1 = aG0 + (size_t)16 * lda;
  const uint16_t* bG0 = BT + (size_t)(Nbase + 32 * w + rsub) * ldb + kStart + kg * 8;
  const uint16_t* bG1 = bG0 + (size_t)16 * ldb;
  uint16_t* aL0 = As + (2 * w) * 512;  uint16_t* aL1 = aL0 + 512;
  uint16_t* bL0 = Bs + (2 * w) * 512;  uint16_t* bL1 = bL0 + 512;

  const int q = L >> 4, lr = L & 15;
  const int slot = q ^ ((L >> 1) & 3);
  const uint16_t* aF = As + (wm + lr) * 32 + slot * 8;
  const uint16_t* bF = Bs + (wn + lr) * 32 + slot * 8;

  for (int ks = 0; ks < kSteps; ks++) {
    __syncthreads();
    gll16(aG0, aL0); gll16(aG1, aL1);
    gll16(bG0, bL0); gll16(bG1, bL1);
    __syncthreads();

    short8 a0 = *(const short8*)(aF);
    short8 a1 = *(const short8*)(aF + 512);
    short8 a2 = *(const short8*)(aF + 1024);
    short8 a3 = *(const short8*)(aF + 1536);
    short8 b0 = *(const short8*)(bF);
    short8 b1 = *(const short8*)(bF + 512);
    short8 b2 = *(const short8*)(bF + 1024);
    short8 b3 = *(const short8*)(bF + 1536);

    acc[0][0] = __builtin_amdgcn_mfma_f32_16x16x32_bf16(a0, b0, acc[0][0], 0, 0, 0);
    acc[0][1] = __builtin_amdgcn_mfma_f32_16x16x32_bf16(a0, b1, acc[0][1], 0, 0, 0);
    acc[0][2] = __builtin_amdgcn_mfma_f32_16x16x32_bf16(a0, b2, acc[0][2], 0, 0, 0);
    acc[0][3] = __builtin_amdgcn_mfma_f32_16x16x32_bf16(a0, b3, acc[0][3], 0, 0, 0);
    acc[1][0] = __builtin_amdgcn_mfma_f32_16x16x32_bf16(a1, b0, acc[1][0], 0, 0, 0);
    acc[1][1] = __builtin_amdgcn_mfma_f32_16x16x32_bf16(a1, b1, acc[1][1], 0, 0, 0);
    acc[1][2] = __builtin_amdgcn_mfma_f32_16x16x32_bf16(a1, b2, acc[1][2], 0, 0, 0);
    acc[1][3] = __builtin_amdgcn_mfma_f32_16x16x32_bf16(a1, b3, acc[1][3], 0, 0, 0);
    acc[2][0] = __builtin_amdgcn_mfma_f32_16x16x32_bf16(a2, b0, acc[2][0], 0, 0, 0);
    acc[2][1] = __builtin_amdgcn_mfma_f32_16x16x32_bf16(a2, b1, acc[2][1], 0, 0, 0);
    acc[2][2] = __builtin_amdgcn_mfma_f32_16x16x32_bf16(a2, b2, acc[2][2], 0, 0, 0);
    acc[2][3] = __builtin_amdgcn_mfma_f32_16x16x32_bf16(a2, b3, acc[2][3], 0, 0, 0);
    acc[3][0] = __builtin_amdgcn_mfma_f32_16x16x32_bf16(a3, b0, acc[3][0], 0, 0, 0);
    acc[3][1] = __builtin_amdgcn_mfma_f32_16x16x32_bf16(a3, b1, acc[3][1], 0, 0, 0);
    acc[3][2] = __builtin_amdgcn_mfma_f32_16x16x32_bf16(a3, b2, acc[3][2], 0, 0, 0);
    acc[3][3] = __builtin_amdgcn_mfma_f32_16x16x32_bf16(a3, b3, acc[3][3], 0, 0, 0);

    aG0 += 32; aG1 += 32; bG0 += 32; bG1 += 32;
  }
}

__device__ __forceinline__ void init_acc(float4v acc[4][4]) {
  float4v zero = {0.f, 0.f, 0.f, 0.f};
#pragma unroll
  for (int i = 0; i < 4; i++)
#pragma unroll
    for (int j = 0; j < 4; j++) acc[i][j] = zero;
}

// bf16 partial store, 16x16 C/D layout: row=q*4+r, col=lr
__device__ __forceinline__ void store_partial_bf16(
    float4v acc[4][4], uint16_t* Pz, int ldc, int Mbase, int Nbase)
{
  const int t = threadIdx.x, w = t >> 6, L = t & 63;
  const int wm = (w & 1) * 64, wn = (w >> 1) * 64, q = L >> 4, lr = L & 15;
#pragma unroll
  for (int mi = 0; mi < 4; mi++)
#pragma unroll
    for (int ni = 0; ni < 4; ni++) {
      int row = Mbase + wm + mi * 16 + q * 4;
      int col = Nbase + wn + ni * 16 + lr;
      uint16_t* pp = Pz + (size_t)row * ldc + col;
      pp[0]       = f2bf(acc[mi][ni][0]);
      pp[ldc]     = f2bf(acc[mi][ni][1]);
      pp[2 * ldc] = f2bf(acc[mi][ni][2]);
      pp[3 * ldc] = f2bf(acc[mi][ni][3]);
    }
}

// gemm1: 1D grid, L = x*(16<<ZBITS) + y*(1<<ZBITS) + z  ->  L % 8 keys XCD.
template<int ZBITS, int ZMASK>
__global__ __launch_bounds__(256, 4) void gemm1_kernel(
    const uint16_t* __restrict__ A, const uint16_t* __restrict__ BT,
    int kChunk, uint16_t* __restrict__ P)
{
  __shared__ __align__(16) uint16_t As[4096];
  __shared__ __align__(16) uint16_t Bs[4096];
  float4v acc[4][4];
  init_acc(acc);
  int Lb = blockIdx.x;
  int z = Lb & ZMASK, y = (Lb >> ZBITS) & 15, x = Lb >> (ZBITS + 4);
  gemm_core(A, D_FEAT, BT, D_FEAT, x * 128, y * 128, z * kChunk, kChunk >> 5,
            As, Bs, acc);
  store_partial_bf16(acc, P + (size_t)z * (1024 * 2048), 2048, x * 128, y * 128);
}

// sum bf16 split-K partials + bias + relu -> bf16 (8 elems/thread)
__global__ void reduce_kernel(
    const uint16_t* __restrict__ P, int nsplit, size_t zstride,
    const float* __restrict__ biasLo, const float* __restrict__ biasHi,
    int colSplit, int ldrow, uint16_t* __restrict__ out, int total8)
{
  int tid = blockIdx.x * blockDim.x + threadIdx.x;
  if (tid >= total8) return;
  size_t i8 = (size_t)tid * 8;
  int col = (int)(i8 % (size_t)ldrow);
  float s[8];
#pragma unroll
  for (int e = 0; e < 8; e++) s[e] = 0.f;
  for (int z = 0; z < nsplit; z++) {
    uint4 u = *(const uint4*)(P + (size_t)z * zstride + i8);
    s[0] += bf2f((uint16_t)u.x); s[1] += bf2f((uint16_t)(u.x >> 16));
    s[2] += bf2f((uint16_t)u.y); s[3] += bf2f((uint16_t)(u.y >> 16));
    s[4] += bf2f((uint16_t)u.z); s[5] += bf2f((uint16_t)(u.z >> 16));
    s[6] += bf2f((uint16_t)u.w); s[7] += bf2f((uint16_t)(u.w >> 16));
  }
  const float* bp = (col < colSplit) ? (biasLo + col) : (biasHi + (col - colSplit));
  uint32_t o[4];
#pragma unroll
  for (int e = 0; e < 4; e++) {
    float lo = fmaxf(s[2 * e] + bp[2 * e], 0.f);
    float hi = fmaxf(s[2 * e + 1] + bp[2 * e + 1], 0.f);
    o[e] = (uint32_t)f2bf(lo) | ((uint32_t)f2bf(hi) << 16);
  }
  *(uint4*)(out + i8) = make_uint4(o[0], o[1], o[2], o[3]);
}

// gemm2: h @ W2 full-K (M=1024 N=1024 K=1024), fused bias+relu -> bf16 hb2
__global__ __launch_bounds__(256, 4) void gemm2_kernel(
    const uint16_t* __restrict__ A, const uint16_t* __restrict__ BT,
    const float* __restrict__ bias, uint16_t* __restrict__ out)
{
  __shared__ __align__(16) uint16_t As[4096];
  __shared__ __align__(16) uint16_t Bs[4096];
  float4v acc[4][4];
  init_acc(acc);
  gemm_core(A, 2048, BT, 1024, blockIdx.x * 128, blockIdx.y * 128, 0, 32,
            As, Bs, acc);
  const int t = threadIdx.x, w = t >> 6, L = t & 63;
  const int wm = (w & 1) * 64, wn = (w >> 1) * 64, q = L >> 4, lr = L & 15;
#pragma unroll
  for (int mi = 0; mi < 4; mi++)
#pragma unroll
    for (int ni = 0; ni < 4; ni++) {
      int row = blockIdx.x * 128 + wm + mi * 16 + q * 4;
      int col = blockIdx.y * 128 + wn + ni * 16 + lr;
      float bv = bias[col];
      uint16_t* pp = out + (size_t)row * 1024 + col;
      pp[0]        = f2bf(fmaxf(acc[mi][ni][0] + bv, 0.f));
      pp[1024]     = f2bf(fmaxf(acc[mi][ni][1] + bv, 0.f));
      pp[2 * 1024] = f2bf(fmaxf(acc[mi][ni][2] + bv, 0.f));
      pp[3 * 1024] = f2bf(fmaxf(acc[mi][ni][3] + bv, 0.f));
    }
}

// final layers, full-K, fused bias, direct d_out write. grid (8, 2 heads)
__global__ __launch_bounds__(256, 4) void gemm_final_kernel(
    const uint16_t* __restrict__ hb2, const uint16_t* __restrict__ cc,
    const uint16_t* __restrict__ w3t, const uint16_t* __restrict__ wc2t,
    const float* __restrict__ b3, const float* __restrict__ bc2,
    float* __restrict__ out, int K)
{
  __shared__ __align__(16) uint16_t As[4096];
  __shared__ __align__(16) uint16_t Bs[4096];
  float4v acc[4][4];
  init_acc(acc);
  int head = blockIdx.y;
  const uint16_t* A = head ? cc : hb2;
  int lda = head ? 2048 : 1024;
  const uint16_t* BT = head ? wc2t : w3t;
  const float* bias = head ? bc2 : b3;
  int Ncols = head ? 81 : 4;
  float* ob = head ? (out + 4000) : out;
  int ldo = head ? 81 : 4;

  gemm_core(A, lda, BT, 1024, blockIdx.x * 128, 0, 0, 32, As, Bs, acc);

  const int t = threadIdx.x, w = t >> 6, L = t & 63;
  const int wm = (w & 1) * 64, wn = (w >> 1) * 64, q = L >> 4, lr = L & 15;
#pragma unroll
  for (int mi = 0; mi < 4; mi++)
#pragma unroll
    for (int ni = 0; ni < 4; ni++) {
      int col = wn + ni * 16 + lr;
      if (col < Ncols) {
        float bv = bias[col];
        int row0 = blockIdx.x * 128 + wm + mi * 16 + q * 4;
#pragma unroll
        for (int r = 0; r < 4; r++) {
          int row = row0 + r;
          if (row < K) ob[(size_t)row * ldo + col] = acc[mi][ni][r] + bv;
        }
      }
    }
}

// ---------------------------------------------------------------------------
extern "C" void kernel_launch(void* const* d_in, const int* in_sizes, int n_in,
                              void* d_out, int out_size, void* d_ws, size_t ws_size,
                              hipStream_t stream)
{
  const float* features = (const float*)d_in[0];
  const float* props    = (const float*)d_in[1];
  const float* W1  = (const float*)d_in[2];
  const float* b1  = (const float*)d_in[3];
  const float* W2  = (const float*)d_in[4];
  const float* b2  = (const float*)d_in[5];
  const float* W3  = (const float*)d_in[6];
  const float* b3  = (const float*)d_in[7];
  const float* Wc1 = (const float*)d_in[8];
  const float* bc1 = (const float*)d_in[9];
  const float* Wc2 = (const float*)d_in[10];
  const float* bc2 = (const float*)d_in[11];
  int K = in_sizes[1] / 5;   // 1000

  char* ws = (char*)d_ws;
  size_t off = 0;
  auto take = [&](size_t bytes) { size_t o = off; off = (off + bytes + 255) & ~(size_t)255; return o; };
  uint16_t* featT = (uint16_t*)(ws + take((size_t)2 * 2500 * 256 * 2));
  uint16_t* xb    = (uint16_t*)(ws + take((size_t)MPAD * D_FEAT * 2));
  uint16_t* w1t   = (uint16_t*)(ws + take((size_t)2048 * D_FEAT * 2));
  uint16_t* w2t   = (uint16_t*)(ws + take((size_t)1024 * 1024 * 2));
  uint16_t* w3t   = (uint16_t*)(ws + take((size_t)128 * 1024 * 2));
  uint16_t* wc2t  = (uint16_t*)(ws + take((size_t)128 * 1024 * 2));
  uint16_t* hbcc  = (uint16_t*)(ws + take((size_t)1024 * 2048 * 2));
  uint16_t* hb2   = (uint16_t*)(ws + take((size_t)1024 * 1024 * 2));
  size_t pOff = off;
  uint16_t* Pb = (uint16_t*)(ws + pOff);   // gemm1 bf16 partials
  size_t need8 = pOff + (size_t)8 * 1024 * 2048 * 2;
  int z1 = (ws_size >= need8) ? 8 : 4;

  prep_kernel<<<792, 256, 0, stream>>>(features, W1, Wc1, W2, W3, Wc2,
                                       featT, w1t, w2t, w3t, wc2t);
  roialign_kernel<<<MPAD, 128, 0, stream>>>((const uint32_t*)featT, props,
                                            (uint32_t*)xb, K);
  // gemm1: M=1024 N=2048 K=12544, XCD-swizzled 1D grid, bf16 partials
  if (z1 == 8)
    gemm1_kernel<3, 7><<<1024, 256, 0, stream>>>(xb, w1t, D_FEAT / 8, Pb);
  else
    gemm1_kernel<2, 3><<<512, 256, 0, stream>>>(xb, w1t, D_FEAT / 4, Pb);
  reduce_kernel<<<1024, 256, 0, stream>>>(Pb, z1, (size_t)1024 * 2048,
                                          b1, bc1, 1024, 2048, hbcc, 262144);
  // gemm2: h @ W2, full-K, fused bias+relu
  gemm2_kernel<<<dim3(8, 8), 256, 0, stream>>>(hbcc, w2t, b2, hb2);
  // final: bbox (hb2@W3+b3) / logits (cc@Wc2+bc2), full-K, direct out
  gemm_final_kernel<<<dim3(8, 2), 256, 0, stream>>>(
      hb2, hbcc + 1024, w3t, wc2t, b3, bc2, (float*)d_out, K);
}

// Round 7
// 289.969 us; speedup vs baseline: 1.0759x; 1.0759x over previous
//
#include <hip/hip_runtime.h>
#include <stdint.h>

// ---------------------------------------------------------------------------
// DetectionHead: RoIAlign(1000 rois, 256ch, 7x7, SR=2) + 2-branch MLP.
// R7: K padded 12544->12800 so the GEMM K-loop runs BK=64 double-steps
// (25 barriers/block vs 49 — the step structure is latency-bound, not
// MFMA-bound). LDS = two R2-verified conflict-free 32-k half-tiles.
// prep reverted to tile grid (R6 strip-prep serialized and regressed).
// gemm2/final keep R5's split-K grids (parallelism > dispatch count).
// ---------------------------------------------------------------------------

#define AS1 __attribute__((address_space(1)))
#define AS3 __attribute__((address_space(3)))

typedef __attribute__((ext_vector_type(8))) short short8;    // 8 bf16 = 4 VGPRs
typedef __attribute__((ext_vector_type(4))) float float4v;   // 16x16 MFMA C/D

#define D_FEAT 12544   // 49*256
#define D_PAD  12800   // 64-divisible K (pad zeroed)
#define MPAD   1024    // padded roi count (K=1000)

__device__ __forceinline__ uint16_t f2bf(float f) {
  union { float f; uint32_t u; } v; v.f = f;
  uint32_t r = v.u + 0x7FFFu + ((v.u >> 16) & 1u);   // RNE
  return (uint16_t)(r >> 16);
}
__device__ __forceinline__ float bf2f(uint16_t h) {
  union { uint32_t u; float f; } v; v.u = ((uint32_t)h) << 16;
  return v.f;
}

__device__ __forceinline__ void gll16(const void* g, void* l) {
  __builtin_amdgcn_global_load_lds((const AS1 uint32_t*)g, (AS3 uint32_t*)l, 16, 0, 0);
}

// ---------------------------------------------------------------------------
// prep: tiled transpose + fp32->bf16 (R2-style tile grid; zero tiles for the
// K-pad region). Ranges:
//   [0,320)      features -> featT (ldk 256)
//   [320,6720)   W1|Wc1 -> w1t [2048][12800]; 200 kt x 16 nt x 2 (kt>=196 zero)
//   [6720,6976)  W2 -> w2t (16x16)
//   [6976,7008)  W3 -> w3t [128][1024] pad
//   [7008,7040)  Wc2 -> wc2t
// ---------------------------------------------------------------------------
__global__ __launch_bounds__(256) void prep_kernel(
    const float* __restrict__ features, const float* __restrict__ W1,
    const float* __restrict__ Wc1, const float* __restrict__ W2,
    const float* __restrict__ W3, const float* __restrict__ Wc2,
    uint16_t* __restrict__ featT, uint16_t* __restrict__ w1t,
    uint16_t* __restrict__ w2t, uint16_t* __restrict__ w3t,
    uint16_t* __restrict__ wc2t)
{
  __shared__ __align__(16) uint16_t T[64][72];
  int b = blockIdx.x;
  const float* src; uint16_t* dst;
  int Csrc, Cpad, ldk, rowStride, rowBase, k0, n0;

  if (b < 320) {
    int img = (b >= 160); int bb = b - img * 160;
    int kt = bb & 3, nt = bb >> 2;
    src = features + (size_t)img * 256 * 2500;
    dst = featT + (size_t)img * 2500 * 256;
    Csrc = 2500; Cpad = 2500; ldk = 256; rowStride = 1;
    k0 = kt * 64; n0 = nt * 64; rowBase = k0;
  } else if (b < 6720) {
    int bb = b - 320; int which = (bb >= 3200); bb -= which * 3200;
    int kt = bb % 200, nt = bb / 200;
    src = which ? Wc1 : W1;
    dst = w1t + (size_t)(which ? 1024 : 0) * D_PAD;
    Csrc = (kt >= 196) ? 0 : 1024;       // zero tiles for K-pad
    Cpad = 1024; ldk = D_PAD;
    k0 = kt * 64; n0 = nt * 64;
    int s = k0 >> 8, c0 = k0 & 255;      // gemm-k k' = s*256 + c -> W row c*49+s
    rowBase = c0 * 49 + s; rowStride = 49;
  } else if (b < 6976) {
    int bb = b - 6720; int kt = bb & 15, nt = bb >> 4;
    src = W2; dst = w2t; Csrc = 1024; Cpad = 1024; ldk = 1024;
    rowStride = 1; k0 = kt * 64; n0 = nt * 64; rowBase = k0;
  } else if (b < 7008) {
    int bb = b - 6976; int kt = bb & 15, nt = bb >> 4;
    src = W3; dst = w3t; Csrc = 4; Cpad = 128; ldk = 1024;
    rowStride = 1; k0 = kt * 64; n0 = nt * 64; rowBase = k0;
  } else {
    int bb = b - 7008; int kt = bb & 15, nt = bb >> 4;
    src = Wc2; dst = wc2t; Csrc = 81; Cpad = 128; ldk = 1024;
    rowStride = 1; k0 = kt * 64; n0 = nt * 64; rowBase = k0;
  }

  int t = threadIdx.x;
  int cb = (t & 15) * 4;
  int kb = (t >> 4) * 4;
  float v[4][4];
  if ((Csrc & 3) == 0) {
    int n = n0 + cb;
#pragma unroll
    for (int i = 0; i < 4; i++) {
      if (n < Csrc) {
        const float* p = src + (size_t)(rowBase + (kb + i) * rowStride) * Csrc + n;
        float4 f = *(const float4*)p;
        v[i][0] = f.x; v[i][1] = f.y; v[i][2] = f.z; v[i][3] = f.w;
      } else {
        v[i][0] = v[i][1] = v[i][2] = v[i][3] = 0.f;
      }
    }
  } else {
#pragma unroll
    for (int i = 0; i < 4; i++)
#pragma unroll
      for (int j = 0; j < 4; j++) {
        int n = n0 + cb + j;
        v[i][j] = (n < Csrc) ? src[(size_t)(rowBase + (kb + i) * rowStride) * Csrc + n] : 0.f;
      }
  }
#pragma unroll
  for (int j = 0; j < 4; j++) {
    uint32_t lo = (uint32_t)f2bf(v[0][j]) | ((uint32_t)f2bf(v[1][j]) << 16);
    uint32_t hi = (uint32_t)f2bf(v[2][j]) | ((uint32_t)f2bf(v[3][j]) << 16);
    *(uint2*)&T[cb + j][kb] = make_uint2(lo, hi);
  }
  __syncthreads();
#pragma unroll
  for (int i = 0; i < 2; i++) {
    int n = (t >> 3) + i * 32;
    int c8 = (t & 7) * 8;
    if (n0 + n < Cpad)
      *(uint4*)(dst + (size_t)(n0 + n) * ldk + k0 + c8) = *(const uint4*)&T[n][c8];
  }
}

// ---------------------------------------------------------------------------
// RoIAlign: 128 threads/block, 2 channels/lane. Writes xb [1024][12800] bf16;
// zeroes the K-pad (cols 12544..12800) and all rows >= K.
// ---------------------------------------------------------------------------
__global__ __launch_bounds__(128) void roialign_kernel(
    const uint32_t* __restrict__ featT2, const float* __restrict__ props,
    uint32_t* __restrict__ xb2, int K)
{
  __shared__ float wy0[14], wy1[14], wx0[14], wx1[14];
  __shared__ int iy0[14], iy1[14], ix0[14], ix1[14];
  __shared__ int sb;
  int roi = blockIdx.x;
  int t = threadIdx.x;
  uint32_t* xr = xb2 + (size_t)roi * (D_PAD / 2) + t;
  if (roi >= K) {
    for (int s = 0; s < 50; s++) xr[s * 128] = 0u;   // full 12800-col row
    return;
  }
  if (t < 28) {
    int j = t % 14;
    bool isx = t >= 14;
    const float* p = props + roi * 5;
    float lo = (isx ? p[1] : p[2]) * 0.0625f;
    float hi = (isx ? p[3] : p[4]) * 0.0625f;
    float ext = fmaxf(hi - lo, 1.0f);
    float bin = ext * (1.0f / 7.0f);
    float y = lo + (j + 0.5f) * 0.5f * bin;
    bool valid = (y > -1.0f) && (y < 50.0f);
    float yc = fminf(fmaxf(y, 0.0f), 49.0f);
    int i0 = (int)yc;
    int i1 = min(i0 + 1, 49);
    float fhi = yc - (float)i0;
    float flo = 1.0f - fhi;
    if (!valid) { flo = 0.0f; fhi = 0.0f; }
    if (isx) { ix0[j] = i0; ix1[j] = i1; wx0[j] = flo; wx1[j] = fhi; }
    else     { iy0[j] = i0; iy1[j] = i1; wy0[j] = flo; wy1[j] = fhi; }
  }
  if (t == 0) sb = (int)props[roi * 5];
  __syncthreads();

  const uint32_t* fb = featT2 + (size_t)sb * (2500 * 128) + t;
  for (int py = 0; py < 7; py++) {
    for (int px = 0; px < 7; px++) {
      float acc0 = 0.f, acc1 = 0.f;
#pragma unroll
      for (int sy = 0; sy < 2; sy++) {
        int jy = py * 2 + sy;
        int y0 = iy0[jy], y1 = iy1[jy];
        float a0 = wy0[jy], a1 = wy1[jy];
#pragma unroll
        for (int sx = 0; sx < 2; sx++) {
          int jx = px * 2 + sx;
          int x0 = ix0[jx], x1 = ix1[jx];
          float b0 = wx0[jx], b1 = wx1[jx];
          uint32_t u00 = fb[(y0 * 50 + x0) * 128];
          uint32_t u01 = fb[(y0 * 50 + x1) * 128];
          uint32_t u10 = fb[(y1 * 50 + x0) * 128];
          uint32_t u11 = fb[(y1 * 50 + x1) * 128];
          acc0 += a0 * (b0 * bf2f((uint16_t)u00) + b1 * bf2f((uint16_t)u01))
                + a1 * (b0 * bf2f((uint16_t)u10) + b1 * bf2f((uint16_t)u11));
          acc1 += a0 * (b0 * bf2f((uint16_t)(u00 >> 16)) + b1 * bf2f((uint16_t)(u01 >> 16)))
                + a1 * (b0 * bf2f((uint16_t)(u10 >> 16)) + b1 * bf2f((uint16_t)(u11 >> 16)));
        }
      }
      uint32_t packed = (uint32_t)f2bf(acc0 * 0.25f) | ((uint32_t)f2bf(acc1 * 0.25f) << 16);
      xr[(py * 7 + px) * 128] = packed;
    }
  }
  xr[6272] = 0u;   // K-pad: uint 6272+t covers cols 12544..12800
}

// ---------------------------------------------------------------------------
// GEMM core: 128x128 C-tile, BK=64 double-step (two verified-conflict-free
// 32-k half-tiles at +4096 ushorts), 16x16x32 MFMA, 32 MFMA per barrier.
// ---------------------------------------------------------------------------
__device__ __forceinline__ void gemm_core(
    const uint16_t* __restrict__ A, int lda,
    const uint16_t* __restrict__ BT, int ldb,
    int Mbase, int Nbase, int kStart, int kSteps,   // kSteps = K/64 steps
    uint16_t* As, uint16_t* Bs, float4v acc[4][4])
{
  const int t = threadIdx.x;
  const int w = t >> 6, L = t & 63;
  const int wm = (w & 1) * 64, wn = (w >> 1) * 64;

  const int kg = (L & 3) ^ ((L >> 3) & 3);   // XOR swizzle on k-group
  const int rsub = L >> 2;
  const uint16_t* aG0 = A + (size_t)(Mbase + 32 * w + rsub) * lda + kStart + kg * 8;
  const uint16_t* aG1 = aG0 + (size_t)16 * lda;
  const uint16_t* bG0 = BT + (size_t)(Nbase + 32 * w + rsub) * ldb + kStart + kg * 8;
  const uint16_t* bG1 = bG0 + (size_t)16 * ldb;
  uint16_t* aL0 = As + (2 * w) * 512;  uint16_t* aL1 = aL0 + 512;
  uint16_t* bL0 = Bs + (2 * w) * 512;  uint16_t* bL1 = bL0 + 512;

  const int q = L >> 4, lr = L & 15;
  const int slot = q ^ ((L >> 1) & 3);
  const uint16_t* aF = As + (wm + lr) * 32 + slot * 8;
  const uint16_t* bF = Bs + (wn + lr) * 32 + slot * 8;

  for (int ks = 0; ks < kSteps; ks++) {
    __syncthreads();
    // half 0 (k..k+32) and half 1 (k+32..k+64); half-1 LDS at +4096
    gll16(aG0, aL0);        gll16(aG1, aL1);
    gll16(aG0 + 32, aL0 + 4096); gll16(aG1 + 32, aL1 + 4096);
    gll16(bG0, bL0);        gll16(bG1, bL1);
    gll16(bG0 + 32, bL0 + 4096); gll16(bG1 + 32, bL1 + 4096);
    __syncthreads();

#pragma unroll
    for (int h = 0; h < 2; h++) {
      const uint16_t* aFh = aF + h * 4096;
      const uint16_t* bFh = bF + h * 4096;
      short8 a0 = *(const short8*)(aFh);
      short8 a1 = *(const short8*)(aFh + 512);
      short8 a2 = *(const short8*)(aFh + 1024);
      short8 a3 = *(const short8*)(aFh + 1536);
      short8 b0 = *(const short8*)(bFh);
      short8 b1 = *(const short8*)(bFh + 512);
      short8 b2 = *(const short8*)(bFh + 1024);
      short8 b3 = *(const short8*)(bFh + 1536);

      acc[0][0] = __builtin_amdgcn_mfma_f32_16x16x32_bf16(a0, b0, acc[0][0], 0, 0, 0);
      acc[0][1] = __builtin_amdgcn_mfma_f32_16x16x32_bf16(a0, b1, acc[0][1], 0, 0, 0);
      acc[0][2] = __builtin_amdgcn_mfma_f32_16x16x32_bf16(a0, b2, acc[0][2], 0, 0, 0);
      acc[0][3] = __builtin_amdgcn_mfma_f32_16x16x32_bf16(a0, b3, acc[0][3], 0, 0, 0);
      acc[1][0] = __builtin_amdgcn_mfma_f32_16x16x32_bf16(a1, b0, acc[1][0], 0, 0, 0);
      acc[1][1] = __builtin_amdgcn_mfma_f32_16x16x32_bf16(a1, b1, acc[1][1], 0, 0, 0);
      acc[1][2] = __builtin_amdgcn_mfma_f32_16x16x32_bf16(a1, b2, acc[1][2], 0, 0, 0);
      acc[1][3] = __builtin_amdgcn_mfma_f32_16x16x32_bf16(a1, b3, acc[1][3], 0, 0, 0);
      acc[2][0] = __builtin_amdgcn_mfma_f32_16x16x32_bf16(a2, b0, acc[2][0], 0, 0, 0);
      acc[2][1] = __builtin_amdgcn_mfma_f32_16x16x32_bf16(a2, b1, acc[2][1], 0, 0, 0);
      acc[2][2] = __builtin_amdgcn_mfma_f32_16x16x32_bf16(a2, b2, acc[2][2], 0, 0, 0);
      acc[2][3] = __builtin_amdgcn_mfma_f32_16x16x32_bf16(a2, b3, acc[2][3], 0, 0, 0);
      acc[3][0] = __builtin_amdgcn_mfma_f32_16x16x32_bf16(a3, b0, acc[3][0], 0, 0, 0);
      acc[3][1] = __builtin_amdgcn_mfma_f32_16x16x32_bf16(a3, b1, acc[3][1], 0, 0, 0);
      acc[3][2] = __builtin_amdgcn_mfma_f32_16x16x32_bf16(a3, b2, acc[3][2], 0, 0, 0);
      acc[3][3] = __builtin_amdgcn_mfma_f32_16x16x32_bf16(a3, b3, acc[3][3], 0, 0, 0);
    }
    aG0 += 64; aG1 += 64; bG0 += 64; bG1 += 64;
  }
}

__device__ __forceinline__ void init_acc(float4v acc[4][4]) {
  float4v zero = {0.f, 0.f, 0.f, 0.f};
#pragma unroll
  for (int i = 0; i < 4; i++)
#pragma unroll
    for (int j = 0; j < 4; j++) acc[i][j] = zero;
}

// bf16 partial store, 16x16 C/D layout: row=q*4+r, col=lr
__device__ __forceinline__ void store_partial_bf16(
    float4v acc[4][4], uint16_t* Pz, int ldc, int Mbase, int Nbase)
{
  const int t = threadIdx.x, w = t >> 6, L = t & 63;
  const int wm = (w & 1) * 64, wn = (w >> 1) * 64, q = L >> 4, lr = L & 15;
#pragma unroll
  for (int mi = 0; mi < 4; mi++)
#pragma unroll
    for (int ni = 0; ni < 4; ni++) {
      int row = Mbase + wm + mi * 16 + q * 4;
      int col = Nbase + wn + ni * 16 + lr;
      uint16_t* pp = Pz + (size_t)row * ldc + col;
      pp[0]       = f2bf(acc[mi][ni][0]);
      pp[ldc]     = f2bf(acc[mi][ni][1]);
      pp[2 * ldc] = f2bf(acc[mi][ni][2]);
      pp[3 * ldc] = f2bf(acc[mi][ni][3]);
    }
}

// fp32 partial store (final layer)
__device__ __forceinline__ void store_partial_f32(
    float4v acc[4][4], float* Pz, int ldc, int Mbase, int Nbase)
{
  const int t = threadIdx.x, w = t >> 6, L = t & 63;
  const int wm = (w & 1) * 64, wn = (w >> 1) * 64, q = L >> 4, lr = L & 15;
#pragma unroll
  for (int mi = 0; mi < 4; mi++)
#pragma unroll
    for (int ni = 0; ni < 4; ni++) {
      int row = Mbase + wm + mi * 16 + q * 4;
      int col = Nbase + wn + ni * 16 + lr;
      float* pp = Pz + (size_t)row * ldc + col;
      pp[0]       = acc[mi][ni][0];
      pp[ldc]     = acc[mi][ni][1];
      pp[2 * ldc] = acc[mi][ni][2];
      pp[3 * ldc] = acc[mi][ni][3];
    }
}

// gemm1: 1D grid, L = x*(16<<ZBITS) + y*(1<<ZBITS) + z  ->  L % 8 keys XCD.
template<int ZBITS, int ZMASK>
__global__ __launch_bounds__(256, 4) void gemm1_kernel(
    const uint16_t* __restrict__ A, const uint16_t* __restrict__ BT,
    int kChunk, uint16_t* __restrict__ P)
{
  __shared__ __align__(16) uint16_t As[8192];
  __shared__ __align__(16) uint16_t Bs[8192];
  float4v acc[4][4];
  init_acc(acc);
  int Lb = blockIdx.x;
  int z = Lb & ZMASK, y = (Lb >> ZBITS) & 15, x = Lb >> (ZBITS + 4);
  gemm_core(A, D_PAD, BT, D_PAD, x * 128, y * 128, z * kChunk, kChunk >> 6,
            As, Bs, acc);
  store_partial_bf16(acc, P + (size_t)z * (1024 * 2048), 2048, x * 128, y * 128);
}

// sum bf16 split-K partials + bias + relu -> bf16 (8 elems/thread)
__global__ void reduce_kernel(
    const uint16_t* __restrict__ P, int nsplit, size_t zstride,
    const float* __restrict__ biasLo, const float* __restrict__ biasHi,
    int colSplit, int ldrow, uint16_t* __restrict__ out, int total8)
{
  int tid = blockIdx.x * blockDim.x + threadIdx.x;
  if (tid >= total8) return;
  size_t i8 = (size_t)tid * 8;
  int col = (int)(i8 % (size_t)ldrow);
  float s[8];
#pragma unroll
  for (int e = 0; e < 8; e++) s[e] = 0.f;
  for (int z = 0; z < nsplit; z++) {
    uint4 u = *(const uint4*)(P + (size_t)z * zstride + i8);
    s[0] += bf2f((uint16_t)u.x); s[1] += bf2f((uint16_t)(u.x >> 16));
    s[2] += bf2f((uint16_t)u.y); s[3] += bf2f((uint16_t)(u.y >> 16));
    s[4] += bf2f((uint16_t)u.z); s[5] += bf2f((uint16_t)(u.z >> 16));
    s[6] += bf2f((uint16_t)u.w); s[7] += bf2f((uint16_t)(u.w >> 16));
  }
  const float* bp = (col < colSplit) ? (biasLo + col) : (biasHi + (col - colSplit));
  uint32_t o[4];
#pragma unroll
  for (int e = 0; e < 4; e++) {
    float lo = fmaxf(s[2 * e] + bp[2 * e], 0.f);
    float hi = fmaxf(s[2 * e + 1] + bp[2 * e + 1], 0.f);
    o[e] = (uint32_t)f2bf(lo) | ((uint32_t)f2bf(hi) << 16);
  }
  *(uint4*)(out + i8) = make_uint4(o[0], o[1], o[2], o[3]);
}

// generic 3D split-K partial GEMM (gemm2), bf16 partials
__global__ __launch_bounds__(256, 4) void gemm_partial_kernel(
    const uint16_t* __restrict__ A, int lda,
    const uint16_t* __restrict__ BT, int ldb,
    int kChunk, uint16_t* __restrict__ P, int ldc, size_t zstride)
{
  __shared__ __align__(16) uint16_t As[8192];
  __shared__ __align__(16) uint16_t Bs[8192];
  float4v acc[4][4];
  init_acc(acc);
  gemm_core(A, lda, BT, ldb, blockIdx.x * 128, blockIdx.y * 128,
            blockIdx.z * kChunk, kChunk >> 6, As, Bs, acc);
  store_partial_bf16(acc, P + (size_t)blockIdx.z * zstride, ldc,
                     blockIdx.x * 128, blockIdx.y * 128);
}

// final layer partials: grid (8, 2 heads, 4 z); P layout [z][1024][256] fp32
__global__ __launch_bounds__(256, 4) void gemm_final_kernel(
    const uint16_t* __restrict__ hb2, const uint16_t* __restrict__ cc,
    const uint16_t* __restrict__ w3t, const uint16_t* __restrict__ wc2t,
    float* __restrict__ P)
{
  __shared__ __align__(16) uint16_t As[8192];
  __shared__ __align__(16) uint16_t Bs[8192];
  float4v acc[4][4];
  init_acc(acc);
  int head = blockIdx.y, z = blockIdx.z;
  const uint16_t* A = head ? cc : hb2;
  int lda = head ? 2048 : 1024;
  const uint16_t* BT = head ? wc2t : w3t;
  gemm_core(A, lda, BT, 1024, blockIdx.x * 128, 0, z * 256, 4, As, Bs, acc);
  store_partial_f32(acc, P + (size_t)z * (1024 * 256), 256, blockIdx.x * 128, head * 128);
}

// sum final partials + bias -> d_out (bbox then logits, flat)
__global__ void reduce3_kernel(
    const float* __restrict__ P, const float* __restrict__ b3,
    const float* __restrict__ bc2, float* __restrict__ out, int K)
{
  int tid = blockIdx.x * blockDim.x + threadIdx.x;
  if (tid >= K * 85) return;
  int row = tid / 85, c = tid - row * 85;
  int head = (c >= 4);
  int col = head ? (c - 4) : c;
  int pc = head * 128 + col;
  float s = 0.f;
#pragma unroll
  for (int z = 0; z < 4; z++) s += P[(size_t)z * (1024 * 256) + row * 256 + pc];
  s += head ? bc2[col] : b3[col];
  if (head) out[4000 + row * 81 + col] = s;
  else      out[row * 4 + col] = s;
}

// ---------------------------------------------------------------------------
extern "C" void kernel_launch(void* const* d_in, const int* in_sizes, int n_in,
                              void* d_out, int out_size, void* d_ws, size_t ws_size,
                              hipStream_t stream)
{
  const float* features = (const float*)d_in[0];
  const float* props    = (const float*)d_in[1];
  const float* W1  = (const float*)d_in[2];
  const float* b1  = (const float*)d_in[3];
  const float* W2  = (const float*)d_in[4];
  const float* b2  = (const float*)d_in[5];
  const float* W3  = (const float*)d_in[6];
  const float* b3  = (const float*)d_in[7];
  const float* Wc1 = (const float*)d_in[8];
  const float* bc1 = (const float*)d_in[9];
  const float* Wc2 = (const float*)d_in[10];
  const float* bc2 = (const float*)d_in[11];
  int K = in_sizes[1] / 5;   // 1000

  char* ws = (char*)d_ws;
  size_t off = 0;
  auto take = [&](size_t bytes) { size_t o = off; off = (off + bytes + 255) & ~(size_t)255; return o; };
  uint16_t* featT = (uint16_t*)(ws + take((size_t)2 * 2500 * 256 * 2));
  uint16_t* xb    = (uint16_t*)(ws + take((size_t)MPAD * D_PAD * 2));
  uint16_t* w1t   = (uint16_t*)(ws + take((size_t)2048 * D_PAD * 2));
  uint16_t* w2t   = (uint16_t*)(ws + take((size_t)1024 * 1024 * 2));
  uint16_t* w3t   = (uint16_t*)(ws + take((size_t)128 * 1024 * 2));
  uint16_t* wc2t  = (uint16_t*)(ws + take((size_t)128 * 1024 * 2));
  uint16_t* hbcc  = (uint16_t*)(ws + take((size_t)1024 * 2048 * 2));
  uint16_t* hb2   = (uint16_t*)(ws + take((size_t)1024 * 1024 * 2));
  size_t pOff = off;
  uint16_t* Pb = (uint16_t*)(ws + pOff);   // bf16 partial view
  float*    Pf = (float*)(ws + pOff);      // fp32 partial view (final layer)
  size_t need8 = pOff + (size_t)8 * 1024 * 2048 * 2;
  int z1 = (ws_size >= need8) ? 8 : 4;

  prep_kernel<<<7040, 256, 0, stream>>>(features, W1, Wc1, W2, W3, Wc2,
                                        featT, w1t, w2t, w3t, wc2t);
  roialign_kernel<<<MPAD, 128, 0, stream>>>((const uint32_t*)featT, props,
                                            (uint32_t*)xb, K);
  // gemm1: M=1024 N=2048 K=12800(pad), XCD-swizzled 1D grid, bf16 partials
  if (z1 == 8)
    gemm1_kernel<3, 7><<<1024, 256, 0, stream>>>(xb, w1t, D_PAD / 8, Pb);
  else
    gemm1_kernel<2, 3><<<512, 256, 0, stream>>>(xb, w1t, D_PAD / 4, Pb);
  reduce_kernel<<<1024, 256, 0, stream>>>(Pb, z1, (size_t)1024 * 2048,
                                          b1, bc1, 1024, 2048, hbcc, 262144);
  // gemm2: h @ W2, M=1024 N=1024 K=1024, split-K=8 (2 double-steps/block)
  gemm_partial_kernel<<<dim3(8, 8, 8), 256, 0, stream>>>(
      hbcc, 2048, w2t, 1024, 128, Pb, 1024, (size_t)1024 * 1024);
  reduce_kernel<<<512, 256, 0, stream>>>(Pb, 8, (size_t)1024 * 1024,
                                         b2, b2, 1024, 1024, hb2, 131072);
  // final: bbox (hb2@W3) / logits (cc@Wc2), split-K=4 fp32 partials
  gemm_final_kernel<<<dim3(8, 2, 4), 256, 0, stream>>>(hb2, hbcc + 1024, w3t, wc2t, Pf);
  reduce3_kernel<<<(K * 85 + 255) / 256, 256, 0, stream>>>(Pf, b3, bc2, (float*)d_out, K);
}

// Round 8
// 283.460 us; speedup vs baseline: 1.1006x; 1.0230x over previous
//
#include <hip/hip_runtime.h>
#include <stdint.h>

// ---------------------------------------------------------------------------
// DetectionHead: RoIAlign(1000 rois, 256ch, 7x7, SR=2) + 2-branch MLP.
// R8: gemm1 gets a 256x128 C-tile core (2x arithmetic intensity per staged
// LDS byte — R7 counters show gemm1 is L2-staging-BW-bound at ~13 TB/s).
// 4 waves x (64 rows x 128 cols), 128 AGPR acc, LDS 48KB, 2 blocks/CU,
// grid 4x16x8=512 = one co-resident generation. Everything else = R7.
// ---------------------------------------------------------------------------

#define AS1 __attribute__((address_space(1)))
#define AS3 __attribute__((address_space(3)))

typedef __attribute__((ext_vector_type(8))) short short8;    // 8 bf16 = 4 VGPRs
typedef __attribute__((ext_vector_type(4))) float float4v;   // 16x16 MFMA C/D

#define D_FEAT 12544   // 49*256
#define D_PAD  12800   // 64-divisible K (pad zeroed)
#define MPAD   1024    // padded roi count (K=1000)

__device__ __forceinline__ uint16_t f2bf(float f) {
  union { float f; uint32_t u; } v; v.f = f;
  uint32_t r = v.u + 0x7FFFu + ((v.u >> 16) & 1u);   // RNE
  return (uint16_t)(r >> 16);
}
__device__ __forceinline__ float bf2f(uint16_t h) {
  union { uint32_t u; float f; } v; v.u = ((uint32_t)h) << 16;
  return v.f;
}

__device__ __forceinline__ void gll16(const void* g, void* l) {
  __builtin_amdgcn_global_load_lds((const AS1 uint32_t*)g, (AS3 uint32_t*)l, 16, 0, 0);
}

// ---------------------------------------------------------------------------
// prep: tiled transpose + fp32->bf16 (unchanged from R7)
// ---------------------------------------------------------------------------
__global__ __launch_bounds__(256) void prep_kernel(
    const float* __restrict__ features, const float* __restrict__ W1,
    const float* __restrict__ Wc1, const float* __restrict__ W2,
    const float* __restrict__ W3, const float* __restrict__ Wc2,
    uint16_t* __restrict__ featT, uint16_t* __restrict__ w1t,
    uint16_t* __restrict__ w2t, uint16_t* __restrict__ w3t,
    uint16_t* __restrict__ wc2t)
{
  __shared__ __align__(16) uint16_t T[64][72];
  int b = blockIdx.x;
  const float* src; uint16_t* dst;
  int Csrc, Cpad, ldk, rowStride, rowBase, k0, n0;

  if (b < 320) {
    int img = (b >= 160); int bb = b - img * 160;
    int kt = bb & 3, nt = bb >> 2;
    src = features + (size_t)img * 256 * 2500;
    dst = featT + (size_t)img * 2500 * 256;
    Csrc = 2500; Cpad = 2500; ldk = 256; rowStride = 1;
    k0 = kt * 64; n0 = nt * 64; rowBase = k0;
  } else if (b < 6720) {
    int bb = b - 320; int which = (bb >= 3200); bb -= which * 3200;
    int kt = bb % 200, nt = bb / 200;
    src = which ? Wc1 : W1;
    dst = w1t + (size_t)(which ? 1024 : 0) * D_PAD;
    Csrc = (kt >= 196) ? 0 : 1024;       // zero tiles for K-pad
    Cpad = 1024; ldk = D_PAD;
    k0 = kt * 64; n0 = nt * 64;
    int s = k0 >> 8, c0 = k0 & 255;      // gemm-k k' = s*256 + c -> W row c*49+s
    rowBase = c0 * 49 + s; rowStride = 49;
  } else if (b < 6976) {
    int bb = b - 6720; int kt = bb & 15, nt = bb >> 4;
    src = W2; dst = w2t; Csrc = 1024; Cpad = 1024; ldk = 1024;
    rowStride = 1; k0 = kt * 64; n0 = nt * 64; rowBase = k0;
  } else if (b < 7008) {
    int bb = b - 6976; int kt = bb & 15, nt = bb >> 4;
    src = W3; dst = w3t; Csrc = 4; Cpad = 128; ldk = 1024;
    rowStride = 1; k0 = kt * 64; n0 = nt * 64; rowBase = k0;
  } else {
    int bb = b - 7008; int kt = bb & 15, nt = bb >> 4;
    src = Wc2; dst = wc2t; Csrc = 81; Cpad = 128; ldk = 1024;
    rowStride = 1; k0 = kt * 64; n0 = nt * 64; rowBase = k0;
  }

  int t = threadIdx.x;
  int cb = (t & 15) * 4;
  int kb = (t >> 4) * 4;
  float v[4][4];
  if ((Csrc & 3) == 0) {
    int n = n0 + cb;
#pragma unroll
    for (int i = 0; i < 4; i++) {
      if (n < Csrc) {
        const float* p = src + (size_t)(rowBase + (kb + i) * rowStride) * Csrc + n;
        float4 f = *(const float4*)p;
        v[i][0] = f.x; v[i][1] = f.y; v[i][2] = f.z; v[i][3] = f.w;
      } else {
        v[i][0] = v[i][1] = v[i][2] = v[i][3] = 0.f;
      }
    }
  } else {
#pragma unroll
    for (int i = 0; i < 4; i++)
#pragma unroll
      for (int j = 0; j < 4; j++) {
        int n = n0 + cb + j;
        v[i][j] = (n < Csrc) ? src[(size_t)(rowBase + (kb + i) * rowStride) * Csrc + n] : 0.f;
      }
  }
#pragma unroll
  for (int j = 0; j < 4; j++) {
    uint32_t lo = (uint32_t)f2bf(v[0][j]) | ((uint32_t)f2bf(v[1][j]) << 16);
    uint32_t hi = (uint32_t)f2bf(v[2][j]) | ((uint32_t)f2bf(v[3][j]) << 16);
    *(uint2*)&T[cb + j][kb] = make_uint2(lo, hi);
  }
  __syncthreads();
#pragma unroll
  for (int i = 0; i < 2; i++) {
    int n = (t >> 3) + i * 32;
    int c8 = (t & 7) * 8;
    if (n0 + n < Cpad)
      *(uint4*)(dst + (size_t)(n0 + n) * ldk + k0 + c8) = *(const uint4*)&T[n][c8];
  }
}

// ---------------------------------------------------------------------------
// RoIAlign (unchanged from R7): 128 threads, 2ch/lane, zeroes K-pad.
// ---------------------------------------------------------------------------
__global__ __launch_bounds__(128) void roialign_kernel(
    const uint32_t* __restrict__ featT2, const float* __restrict__ props,
    uint32_t* __restrict__ xb2, int K)
{
  __shared__ float wy0[14], wy1[14], wx0[14], wx1[14];
  __shared__ int iy0[14], iy1[14], ix0[14], ix1[14];
  __shared__ int sb;
  int roi = blockIdx.x;
  int t = threadIdx.x;
  uint32_t* xr = xb2 + (size_t)roi * (D_PAD / 2) + t;
  if (roi >= K) {
    for (int s = 0; s < 50; s++) xr[s * 128] = 0u;
    return;
  }
  if (t < 28) {
    int j = t % 14;
    bool isx = t >= 14;
    const float* p = props + roi * 5;
    float lo = (isx ? p[1] : p[2]) * 0.0625f;
    float hi = (isx ? p[3] : p[4]) * 0.0625f;
    float ext = fmaxf(hi - lo, 1.0f);
    float bin = ext * (1.0f / 7.0f);
    float y = lo + (j + 0.5f) * 0.5f * bin;
    bool valid = (y > -1.0f) && (y < 50.0f);
    float yc = fminf(fmaxf(y, 0.0f), 49.0f);
    int i0 = (int)yc;
    int i1 = min(i0 + 1, 49);
    float fhi = yc - (float)i0;
    float flo = 1.0f - fhi;
    if (!valid) { flo = 0.0f; fhi = 0.0f; }
    if (isx) { ix0[j] = i0; ix1[j] = i1; wx0[j] = flo; wx1[j] = fhi; }
    else     { iy0[j] = i0; iy1[j] = i1; wy0[j] = flo; wy1[j] = fhi; }
  }
  if (t == 0) sb = (int)props[roi * 5];
  __syncthreads();

  const uint32_t* fb = featT2 + (size_t)sb * (2500 * 128) + t;
  for (int py = 0; py < 7; py++) {
    for (int px = 0; px < 7; px++) {
      float acc0 = 0.f, acc1 = 0.f;
#pragma unroll
      for (int sy = 0; sy < 2; sy++) {
        int jy = py * 2 + sy;
        int y0 = iy0[jy], y1 = iy1[jy];
        float a0 = wy0[jy], a1 = wy1[jy];
#pragma unroll
        for (int sx = 0; sx < 2; sx++) {
          int jx = px * 2 + sx;
          int x0 = ix0[jx], x1 = ix1[jx];
          float b0 = wx0[jx], b1 = wx1[jx];
          uint32_t u00 = fb[(y0 * 50 + x0) * 128];
          uint32_t u01 = fb[(y0 * 50 + x1) * 128];
          uint32_t u10 = fb[(y1 * 50 + x0) * 128];
          uint32_t u11 = fb[(y1 * 50 + x1) * 128];
          acc0 += a0 * (b0 * bf2f((uint16_t)u00) + b1 * bf2f((uint16_t)u01))
                + a1 * (b0 * bf2f((uint16_t)u10) + b1 * bf2f((uint16_t)u11));
          acc1 += a0 * (b0 * bf2f((uint16_t)(u00 >> 16)) + b1 * bf2f((uint16_t)(u01 >> 16)))
                + a1 * (b0 * bf2f((uint16_t)(u10 >> 16)) + b1 * bf2f((uint16_t)(u11 >> 16)));
        }
      }
      uint32_t packed = (uint32_t)f2bf(acc0 * 0.25f) | ((uint32_t)f2bf(acc1 * 0.25f) << 16);
      xr[(py * 7 + px) * 128] = packed;
    }
  }
  xr[6272] = 0u;   // K-pad cols 12544..12800
}

// ---------------------------------------------------------------------------
// 128x128 core (R7-measured): BK=64 double-step, used by gemm2/final.
// ---------------------------------------------------------------------------
__device__ __forceinline__ void gemm_core(
    const uint16_t* __restrict__ A, int lda,
    const uint16_t* __restrict__ BT, int ldb,
    int Mbase, int Nbase, int kStart, int kSteps,
    uint16_t* As, uint16_t* Bs, float4v acc[4][4])
{
  const int t = threadIdx.x;
  const int w = t >> 6, L = t & 63;
  const int wm = (w & 1) * 64, wn = (w >> 1) * 64;

  const int kg = (L & 3) ^ ((L >> 3) & 3);
  const int rsub = L >> 2;
  const uint16_t* aG0 = A + (size_t)(Mbase + 32 * w + rsub) * lda + kStart + kg * 8;
  const uint16_t* aG1 = aG0 + (size_t)16 * lda;
  const uint16_t* bG0 = BT + (size_t)(Nbase + 32 * w + rsub) * ldb + kStart + kg * 8;
  const uint16_t* bG1 = bG0 + (size_t)16 * ldb;
  uint16_t* aL0 = As + (2 * w) * 512;  uint16_t* aL1 = aL0 + 512;
  uint16_t* bL0 = Bs + (2 * w) * 512;  uint16_t* bL1 = bL0 + 512;

  const int q = L >> 4, lr = L & 15;
  const int slot = q ^ ((L >> 1) & 3);
  const uint16_t* aF = As + (wm + lr) * 32 + slot * 8;
  const uint16_t* bF = Bs + (wn + lr) * 32 + slot * 8;

  for (int ks = 0; ks < kSteps; ks++) {
    __syncthreads();
    gll16(aG0, aL0);        gll16(aG1, aL1);
    gll16(aG0 + 32, aL0 + 4096); gll16(aG1 + 32, aL1 + 4096);
    gll16(bG0, bL0);        gll16(bG1, bL1);
    gll16(bG0 + 32, bL0 + 4096); gll16(bG1 + 32, bL1 + 4096);
    __syncthreads();

#pragma unroll
    for (int h = 0; h < 2; h++) {
      const uint16_t* aFh = aF + h * 4096;
      const uint16_t* bFh = bF + h * 4096;
      short8 a0 = *(const short8*)(aFh);
      short8 a1 = *(const short8*)(aFh + 512);
      short8 a2 = *(const short8*)(aFh + 1024);
      short8 a3 = *(const short8*)(aFh + 1536);
      short8 b0 = *(const short8*)(bFh);
      short8 b1 = *(const short8*)(bFh + 512);
      short8 b2 = *(const short8*)(bFh + 1024);
      short8 b3 = *(const short8*)(bFh + 1536);

      acc[0][0] = __builtin_amdgcn_mfma_f32_16x16x32_bf16(a0, b0, acc[0][0], 0, 0, 0);
      acc[0][1] = __builtin_amdgcn_mfma_f32_16x16x32_bf16(a0, b1, acc[0][1], 0, 0, 0);
      acc[0][2] = __builtin_amdgcn_mfma_f32_16x16x32_bf16(a0, b2, acc[0][2], 0, 0, 0);
      acc[0][3] = __builtin_amdgcn_mfma_f32_16x16x32_bf16(a0, b3, acc[0][3], 0, 0, 0);
      acc[1][0] = __builtin_amdgcn_mfma_f32_16x16x32_bf16(a1, b0, acc[1][0], 0, 0, 0);
      acc[1][1] = __builtin_amdgcn_mfma_f32_16x16x32_bf16(a1, b1, acc[1][1], 0, 0, 0);
      acc[1][2] = __builtin_amdgcn_mfma_f32_16x16x32_bf16(a1, b2, acc[1][2], 0, 0, 0);
      acc[1][3] = __builtin_amdgcn_mfma_f32_16x16x32_bf16(a1, b3, acc[1][3], 0, 0, 0);
      acc[2][0] = __builtin_amdgcn_mfma_f32_16x16x32_bf16(a2, b0, acc[2][0], 0, 0, 0);
      acc[2][1] = __builtin_amdgcn_mfma_f32_16x16x32_bf16(a2, b1, acc[2][1], 0, 0, 0);
      acc[2][2] = __builtin_amdgcn_mfma_f32_16x16x32_bf16(a2, b2, acc[2][2], 0, 0, 0);
      acc[2][3] = __builtin_amdgcn_mfma_f32_16x16x32_bf16(a2, b3, acc[2][3], 0, 0, 0);
      acc[3][0] = __builtin_amdgcn_mfma_f32_16x16x32_bf16(a3, b0, acc[3][0], 0, 0, 0);
      acc[3][1] = __builtin_amdgcn_mfma_f32_16x16x32_bf16(a3, b1, acc[3][1], 0, 0, 0);
      acc[3][2] = __builtin_amdgcn_mfma_f32_16x16x32_bf16(a3, b2, acc[3][2], 0, 0, 0);
      acc[3][3] = __builtin_amdgcn_mfma_f32_16x16x32_bf16(a3, b3, acc[3][3], 0, 0, 0);
    }
    aG0 += 64; aG1 += 64; bG0 += 64; bG1 += 64;
  }
}

__device__ __forceinline__ void init_acc(float4v acc[4][4]) {
  float4v zero = {0.f, 0.f, 0.f, 0.f};
#pragma unroll
  for (int i = 0; i < 4; i++)
#pragma unroll
    for (int j = 0; j < 4; j++) acc[i][j] = zero;
}

__device__ __forceinline__ void store_partial_bf16(
    float4v acc[4][4], uint16_t* Pz, int ldc, int Mbase, int Nbase)
{
  const int t = threadIdx.x, w = t >> 6, L = t & 63;
  const int wm = (w & 1) * 64, wn = (w >> 1) * 64, q = L >> 4, lr = L & 15;
#pragma unroll
  for (int mi = 0; mi < 4; mi++)
#pragma unroll
    for (int ni = 0; ni < 4; ni++) {
      int row = Mbase + wm + mi * 16 + q * 4;
      int col = Nbase + wn + ni * 16 + lr;
      uint16_t* pp = Pz + (size_t)row * ldc + col;
      pp[0]       = f2bf(acc[mi][ni][0]);
      pp[ldc]     = f2bf(acc[mi][ni][1]);
      pp[2 * ldc] = f2bf(acc[mi][ni][2]);
      pp[3 * ldc] = f2bf(acc[mi][ni][3]);
    }
}

__device__ __forceinline__ void store_partial_f32(
    float4v acc[4][4], float* Pz, int ldc, int Mbase, int Nbase)
{
  const int t = threadIdx.x, w = t >> 6, L = t & 63;
  const int wm = (w & 1) * 64, wn = (w >> 1) * 64, q = L >> 4, lr = L & 15;
#pragma unroll
  for (int mi = 0; mi < 4; mi++)
#pragma unroll
    for (int ni = 0; ni < 4; ni++) {
      int row = Mbase + wm + mi * 16 + q * 4;
      int col = Nbase + wn + ni * 16 + lr;
      float* pp = Pz + (size_t)row * ldc + col;
      pp[0]       = acc[mi][ni][0];
      pp[ldc]     = acc[mi][ni][1];
      pp[2 * ldc] = acc[mi][ni][2];
      pp[3 * ldc] = acc[mi][ni][3];
    }
}

// ---------------------------------------------------------------------------
// gemm1: 256x128 C-tile, BK=64. Wave w: rows [64w,64w+64) x all 128 cols.
// acc[4][8] = 128 AGPR. A LDS 32KB (2 halves of 256x32), B 16KB.
// Staging/frag slot formula slot(m,kg)=kg^((m>>1)&3) — verified pattern.
// 1D grid: z = L&7 (XCD key), y = (L>>3)&15, x = L>>7. 512 blocks, 2/CU.
// ---------------------------------------------------------------------------
__global__ __launch_bounds__(256, 2) void gemm1_kernel(
    const uint16_t* __restrict__ A, const uint16_t* __restrict__ BT,
    int kChunk, uint16_t* __restrict__ P)
{
  __shared__ __align__(16) uint16_t As[16384];   // 2 halves x 256 rows x 32
  __shared__ __align__(16) uint16_t Bs[8192];    // 2 halves x 128 rows x 32
  float4v acc[4][8];
  float4v zero = {0.f, 0.f, 0.f, 0.f};
#pragma unroll
  for (int i = 0; i < 4; i++)
#pragma unroll
    for (int j = 0; j < 8; j++) acc[i][j] = zero;

  const int Lb = blockIdx.x;
  const int z = Lb & 7, y = (Lb >> 3) & 15, x = Lb >> 7;
  const int Mbase = x * 256, Nbase = y * 128, kStart = z * kChunk;
  const int kSteps = kChunk >> 6;

  const int t = threadIdx.x;
  const int w = t >> 6, L = t & 63;
  const int kg = (L & 3) ^ ((L >> 3) & 3);
  const int rsub = L >> 2;

  // A staging: wave w rows [64w, 64w+64) in 4 chunks of 16
  const uint16_t* aG0 = A + (size_t)(Mbase + 64 * w + rsub) * D_PAD + kStart + kg * 8;
  const uint16_t* aG1 = aG0 + (size_t)16 * D_PAD;
  const uint16_t* aG2 = aG0 + (size_t)32 * D_PAD;
  const uint16_t* aG3 = aG0 + (size_t)48 * D_PAD;
  uint16_t* aL0 = As + w * 2048;
  uint16_t* aL1 = aL0 + 512;
  uint16_t* aL2 = aL0 + 1024;
  uint16_t* aL3 = aL0 + 1536;
  // B staging: wave w cols [32w, 32w+32) in 2 chunks of 16
  const uint16_t* bG0 = BT + (size_t)(Nbase + 32 * w + rsub) * D_PAD + kStart + kg * 8;
  const uint16_t* bG1 = bG0 + (size_t)16 * D_PAD;
  uint16_t* bL0 = Bs + w * 1024;
  uint16_t* bL1 = bL0 + 512;

  // fragment read bases
  const int q = L >> 4, lr = L & 15;
  const int slot = q ^ ((L >> 1) & 3);
  const uint16_t* aF = As + (64 * w + lr) * 32 + slot * 8;
  const uint16_t* bF = Bs + lr * 32 + slot * 8;

  for (int ks = 0; ks < kSteps; ks++) {
    __syncthreads();
    gll16(aG0, aL0); gll16(aG1, aL1); gll16(aG2, aL2); gll16(aG3, aL3);
    gll16(aG0 + 32, aL0 + 8192); gll16(aG1 + 32, aL1 + 8192);
    gll16(aG2 + 32, aL2 + 8192); gll16(aG3 + 32, aL3 + 8192);
    gll16(bG0, bL0); gll16(bG1, bL1);
    gll16(bG0 + 32, bL0 + 4096); gll16(bG1 + 32, bL1 + 4096);
    __syncthreads();

#pragma unroll
    for (int h = 0; h < 2; h++) {
      const uint16_t* aFh = aF + h * 8192;
      const uint16_t* bFh = bF + h * 4096;
      short8 a[4], b[8];
#pragma unroll
      for (int mi = 0; mi < 4; mi++) a[mi] = *(const short8*)(aFh + mi * 512);
#pragma unroll
      for (int ni = 0; ni < 8; ni++) b[ni] = *(const short8*)(bFh + ni * 512);
#pragma unroll
      for (int mi = 0; mi < 4; mi++)
#pragma unroll
        for (int ni = 0; ni < 8; ni++)
          acc[mi][ni] = __builtin_amdgcn_mfma_f32_16x16x32_bf16(a[mi], b[ni], acc[mi][ni], 0, 0, 0);
    }
    aG0 += 64; aG1 += 64; aG2 += 64; aG3 += 64;
    bG0 += 64; bG1 += 64;
  }

  // epilogue: bf16 partials to P + z*stride
  uint16_t* Pz = P + (size_t)z * (1024 * 2048);
#pragma unroll
  for (int mi = 0; mi < 4; mi++)
#pragma unroll
    for (int ni = 0; ni < 8; ni++) {
      int row = Mbase + 64 * w + mi * 16 + q * 4;
      int col = Nbase + ni * 16 + lr;
      uint16_t* pp = Pz + (size_t)row * 2048 + col;
      pp[0]        = f2bf(acc[mi][ni][0]);
      pp[2048]     = f2bf(acc[mi][ni][1]);
      pp[2 * 2048] = f2bf(acc[mi][ni][2]);
      pp[3 * 2048] = f2bf(acc[mi][ni][3]);
    }
}

// sum bf16 split-K partials + bias + relu -> bf16 (8 elems/thread)
__global__ void reduce_kernel(
    const uint16_t* __restrict__ P, int nsplit, size_t zstride,
    const float* __restrict__ biasLo, const float* __restrict__ biasHi,
    int colSplit, int ldrow, uint16_t* __restrict__ out, int total8)
{
  int tid = blockIdx.x * blockDim.x + threadIdx.x;
  if (tid >= total8) return;
  size_t i8 = (size_t)tid * 8;
  int col = (int)(i8 % (size_t)ldrow);
  float s[8];
#pragma unroll
  for (int e = 0; e < 8; e++) s[e] = 0.f;
  for (int z = 0; z < nsplit; z++) {
    uint4 u = *(const uint4*)(P + (size_t)z * zstride + i8);
    s[0] += bf2f((uint16_t)u.x); s[1] += bf2f((uint16_t)(u.x >> 16));
    s[2] += bf2f((uint16_t)u.y); s[3] += bf2f((uint16_t)(u.y >> 16));
    s[4] += bf2f((uint16_t)u.z); s[5] += bf2f((uint16_t)(u.z >> 16));
    s[6] += bf2f((uint16_t)u.w); s[7] += bf2f((uint16_t)(u.w >> 16));
  }
  const float* bp = (col < colSplit) ? (biasLo + col) : (biasHi + (col - colSplit));
  uint32_t o[4];
#pragma unroll
  for (int e = 0; e < 4; e++) {
    float lo = fmaxf(s[2 * e] + bp[2 * e], 0.f);
    float hi = fmaxf(s[2 * e + 1] + bp[2 * e + 1], 0.f);
    o[e] = (uint32_t)f2bf(lo) | ((uint32_t)f2bf(hi) << 16);
  }
  *(uint4*)(out + i8) = make_uint4(o[0], o[1], o[2], o[3]);
}

// generic 3D split-K partial GEMM (gemm2), bf16 partials, 128x128 core
__global__ __launch_bounds__(256, 4) void gemm_partial_kernel(
    const uint16_t* __restrict__ A, int lda,
    const uint16_t* __restrict__ BT, int ldb,
    int kChunk, uint16_t* __restrict__ P, int ldc, size_t zstride)
{
  __shared__ __align__(16) uint16_t As[8192];
  __shared__ __align__(16) uint16_t Bs[8192];
  float4v acc[4][4];
  init_acc(acc);
  gemm_core(A, lda, BT, ldb, blockIdx.x * 128, blockIdx.y * 128,
            blockIdx.z * kChunk, kChunk >> 6, As, Bs, acc);
  store_partial_bf16(acc, P + (size_t)blockIdx.z * zstride, ldc,
                     blockIdx.x * 128, blockIdx.y * 128);
}

// final layer partials: grid (8, 2 heads, 4 z); P layout [z][1024][256] fp32
__global__ __launch_bounds__(256, 4) void gemm_final_kernel(
    const uint16_t* __restrict__ hb2, const uint16_t* __restrict__ cc,
    const uint16_t* __restrict__ w3t, const uint16_t* __restrict__ wc2t,
    float* __restrict__ P)
{
  __shared__ __align__(16) uint16_t As[8192];
  __shared__ __align__(16) uint16_t Bs[8192];
  float4v acc[4][4];
  init_acc(acc);
  int head = blockIdx.y, z = blockIdx.z;
  const uint16_t* A = head ? cc : hb2;
  int lda = head ? 2048 : 1024;
  const uint16_t* BT = head ? wc2t : w3t;
  gemm_core(A, lda, BT, 1024, blockIdx.x * 128, 0, z * 256, 4, As, Bs, acc);
  store_partial_f32(acc, P + (size_t)z * (1024 * 256), 256, blockIdx.x * 128, head * 128);
}

// sum final partials + bias -> d_out (bbox then logits, flat)
__global__ void reduce3_kernel(
    const float* __restrict__ P, const float* __restrict__ b3,
    const float* __restrict__ bc2, float* __restrict__ out, int K)
{
  int tid = blockIdx.x * blockDim.x + threadIdx.x;
  if (tid >= K * 85) return;
  int row = tid / 85, c = tid - row * 85;
  int head = (c >= 4);
  int col = head ? (c - 4) : c;
  int pc = head * 128 + col;
  float s = 0.f;
#pragma unroll
  for (int z = 0; z < 4; z++) s += P[(size_t)z * (1024 * 256) + row * 256 + pc];
  s += head ? bc2[col] : b3[col];
  if (head) out[4000 + row * 81 + col] = s;
  else      out[row * 4 + col] = s;
}

// ---------------------------------------------------------------------------
extern "C" void kernel_launch(void* const* d_in, const int* in_sizes, int n_in,
                              void* d_out, int out_size, void* d_ws, size_t ws_size,
                              hipStream_t stream)
{
  const float* features = (const float*)d_in[0];
  const float* props    = (const float*)d_in[1];
  const float* W1  = (const float*)d_in[2];
  const float* b1  = (const float*)d_in[3];
  const float* W2  = (const float*)d_in[4];
  const float* b2  = (const float*)d_in[5];
  const float* W3  = (const float*)d_in[6];
  const float* b3  = (const float*)d_in[7];
  const float* Wc1 = (const float*)d_in[8];
  const float* bc1 = (const float*)d_in[9];
  const float* Wc2 = (const float*)d_in[10];
  const float* bc2 = (const float*)d_in[11];
  int K = in_sizes[1] / 5;   // 1000

  char* ws = (char*)d_ws;
  size_t off = 0;
  auto take = [&](size_t bytes) { size_t o = off; off = (off + bytes + 255) & ~(size_t)255; return o; };
  uint16_t* featT = (uint16_t*)(ws + take((size_t)2 * 2500 * 256 * 2));
  uint16_t* xb    = (uint16_t*)(ws + take((size_t)MPAD * D_PAD * 2));
  uint16_t* w1t   = (uint16_t*)(ws + take((size_t)2048 * D_PAD * 2));
  uint16_t* w2t   = (uint16_t*)(ws + take((size_t)1024 * 1024 * 2));
  uint16_t* w3t   = (uint16_t*)(ws + take((size_t)128 * 1024 * 2));
  uint16_t* wc2t  = (uint16_t*)(ws + take((size_t)128 * 1024 * 2));
  uint16_t* hbcc  = (uint16_t*)(ws + take((size_t)1024 * 2048 * 2));
  uint16_t* hb2   = (uint16_t*)(ws + take((size_t)1024 * 1024 * 2));
  size_t pOff = off;
  uint16_t* Pb = (uint16_t*)(ws + pOff);   // bf16 partial view
  float*    Pf = (float*)(ws + pOff);      // fp32 partial view (final layer)

  prep_kernel<<<7040, 256, 0, stream>>>(features, W1, Wc1, W2, W3, Wc2,
                                        featT, w1t, w2t, w3t, wc2t);
  roialign_kernel<<<MPAD, 128, 0, stream>>>((const uint32_t*)featT, props,
                                            (uint32_t*)xb, K);
  // gemm1: M=1024 N=2048 K=12800(pad), 256x128 tiles, split-K=8, 512 blocks
  gemm1_kernel<<<512, 256, 0, stream>>>(xb, w1t, D_PAD / 8, Pb);
  reduce_kernel<<<1024, 256, 0, stream>>>(Pb, 8, (size_t)1024 * 2048,
                                          b1, bc1, 1024, 2048, hbcc, 262144);
  // gemm2: h @ W2, M=1024 N=1024 K=1024, split-K=8 (2 double-steps/block)
  gemm_partial_kernel<<<dim3(8, 8, 8), 256, 0, stream>>>(
      hbcc, 2048, w2t, 1024, 128, Pb, 1024, (size_t)1024 * 1024);
  reduce_kernel<<<512, 256, 0, stream>>>(Pb, 8, (size_t)1024 * 1024,
                                         b2, b2, 1024, 1024, hb2, 131072);
  // final: bbox (hb2@W3) / logits (cc@Wc2), split-K=4 fp32 partials
  gemm_final_kernel<<<dim3(8, 2, 4), 256, 0, stream>>>(hb2, hbcc + 1024, w3t, wc2t, Pf);
  reduce3_kernel<<<(K * 85 + 255) / 256, 256, 0, stream>>>(Pf, b3, bc2, (float*)d_out, K);
}